// Round 3
// baseline (415.800 us; speedup 1.0000x reference)
//
#include <hip/hip_runtime.h>

typedef __attribute__((ext_vector_type(8))) short bf16x8;
typedef __attribute__((ext_vector_type(4))) float f32x4;

__device__ __forceinline__ unsigned short f2bf(float f){
  unsigned u = __builtin_bit_cast(unsigned, f);
  u += 0x7fffu + ((u >> 16) & 1u);
  return (unsigned short)(u >> 16);
}

__device__ __forceinline__ unsigned cvt_pk_bf16(float lo, float hi){
  unsigned r;
  asm("v_cvt_pk_bf16_f32 %0, %1, %2" : "=v"(r) : "v"(lo), "v"(hi));
  return r;
}

#define ASYNC16(ldsp, gp) __builtin_amdgcn_global_load_lds( \
    (const __attribute__((address_space(1))) unsigned int*)(gp), \
    (__attribute__((address_space(3))) unsigned int*)(ldsp), 16, 0, 0)

// ---- convert x (fp32 [b,56,56,384]) -> bf16 window-ordered [win*49+n][384] ----
__global__ __launch_bounds__(256) void convert_x_kernel(const float* __restrict__ x,
                                                        unsigned short* __restrict__ xb){
  int idx = blockIdx.x*256 + threadIdx.x;          // 100352*96 threads, 4 ch each
  int token = idx / 96, j = idx - token*96;
  int b = token / 3136, rem = token - b*3136;
  int rr = rem / 56, cp = rem - rr*56;
  int p = rr >> 3, h = rr & 7, q = cp >> 3, w = cp & 7;
  int orow = ((b*8 + h)*8 + w)*49 + p*7 + q;
  float4 v = *(const float4*)(x + (size_t)idx*4);
  ushort4 o;
  o.x = f2bf(v.x); o.y = f2bf(v.y); o.z = f2bf(v.z); o.w = f2bf(v.w);
  *(ushort4*)(xb + (size_t)orow*384 + j*4) = o;
}

// ---- convert weights fp32 -> bf16 ----
__global__ __launch_bounds__(256) void convert_w_kernel(const float* __restrict__ wq,
                                                        const float* __restrict__ wo,
                                                        unsigned short* __restrict__ wqb,
                                                        unsigned short* __restrict__ wob){
  int idx = blockIdx.x*256 + threadIdx.x;          // 147456 threads
  if (idx < 110592){
    float4 v = *(const float4*)(wq + (size_t)idx*4);
    ushort4 o; o.x=f2bf(v.x); o.y=f2bf(v.y); o.z=f2bf(v.z); o.w=f2bf(v.w);
    *(ushort4*)(wqb + (size_t)idx*4) = o;
  } else {
    int k = idx - 110592;
    float4 v = *(const float4*)(wo + (size_t)k*4);
    ushort4 o; o.x=f2bf(v.x); o.y=f2bf(v.y); o.z=f2bf(v.z); o.w=f2bf(v.w);
    *(ushort4*)(wob + (size_t)k*4) = o;
  }
}

// ---- bias table [12][q=64][k=64] f32, pre-scaled by log2(e); -inf for k>=49 ----
__global__ __launch_bounds__(256) void build_btab(const float* __restrict__ rel_pos,
                                                  float* __restrict__ btab){
  int idx = blockIdx.x*256 + threadIdx.x;          // 49152
  int head = idx >> 12, rem = idx & 4095;
  int qr = rem >> 6, kc = rem & 63;
  float v;
  if (kc >= 49) v = -__builtin_inff();
  else if (qr >= 49) v = 0.f;
  else {
    int ip = qr/7, iq = qr - ip*7, jp = kc/7, jq = kc - jp*7;
    v = rel_pos[head*169 + (ip-jp+6)*13 + (iq-jq+6)] * 1.4426950408889634f;
  }
  btab[idx] = v;
}

// ---- 128x128 tile bf16 GEMM, C = A @ B^T + bias, K=384 fixed.
// Depth-2 pipelined: counted vmcnt(4), raw barriers, dbuf LDS.
// EPI 0: q(*scale*log2e)/k bf16 [win][head][49][32]; v TRANSPOSED [win][head][32][56].
// EPI 1: write fp32 out un-windowed.
template<int EPI>
__global__ __launch_bounds__(256) void gemm128(const unsigned short* __restrict__ A,
                                               const unsigned short* __restrict__ B,
                                               const float* __restrict__ bias,
                                               unsigned short* __restrict__ qo,
                                               unsigned short* __restrict__ ko,
                                               unsigned short* __restrict__ vo,
                                               float* __restrict__ out)
{
  constexpr int K = 384;
  constexpr int NT = 12;                    // K/32
  __shared__ unsigned short Al[2][128*32];
  __shared__ unsigned short Bl[2][128*32];
  const int tid = threadIdx.x;
  const int lane = tid & 63, wid = tid >> 6;
  const int wr = wid >> 1, wc = wid & 1;
  const int l15 = lane & 15, kg = lane >> 4;

  const unsigned short* Ag = A + ((size_t)blockIdx.x*128 + (tid>>2))*K + (tid&3)*8;
  const unsigned short* Bg = B + ((size_t)blockIdx.y*128 + (tid>>2))*K + (tid&3)*8;

  f32x4 acc[4][4] = {};

#define STAGE(buf, k0) do { \
    ASYNC16(&Al[buf][wid*512],        Ag + (k0)); \
    ASYNC16(&Al[buf][wid*512 + 2048], Ag + (size_t)64*K + (k0)); \
    ASYNC16(&Bl[buf][wid*512],        Bg + (k0)); \
    ASYNC16(&Bl[buf][wid*512 + 2048], Bg + (size_t)64*K + (k0)); \
  } while(0)

  STAGE(0, 0);
  STAGE(1, 32);

#pragma unroll
  for (int t = 0; t < NT; ++t){
    if (t == NT-1) asm volatile("s_waitcnt vmcnt(0)\n\ts_barrier" ::: "memory");
    else           asm volatile("s_waitcnt vmcnt(4)\n\ts_barrier" ::: "memory");

    const unsigned short* Ab = Al[t & 1];
    const unsigned short* Bb = Bl[t & 1];
    bf16x8 af[4], bfv[4];
#pragma unroll
    for (int ti=0; ti<4; ++ti)
      af[ti] = *(const bf16x8*)(Ab + (wr*64 + ti*16 + l15)*32 + kg*8);
#pragma unroll
    for (int tj=0; tj<4; ++tj)
      bfv[tj] = *(const bf16x8*)(Bb + (wc*64 + tj*16 + l15)*32 + kg*8);

    asm volatile("s_waitcnt lgkmcnt(0)\n\ts_barrier" ::: "memory");

    if (t < NT-2) STAGE(t & 1, (t+2)*32);   // refill the buffer just consumed

    __builtin_amdgcn_s_setprio(1);
#pragma unroll
    for (int ti=0; ti<4; ++ti)
#pragma unroll
      for (int tj=0; tj<4; ++tj)
        acc[ti][tj] = __builtin_amdgcn_mfma_f32_16x16x32_bf16(af[ti], bfv[tj], acc[ti][tj], 0,0,0);
    __builtin_amdgcn_s_setprio(0);
  }
#undef STAGE

  const int rbase = blockIdx.x*128 + wr*64 + kg*4;

  if (EPI == 0){
    const int by = blockIdx.y;
    const int t = by / 3;                          // block-uniform: q/k/v select
    const int cb = (by - t*3)*128 + wc*64;         // col base within 384
    if (t < 2){
      unsigned short* __restrict__ Pout = (t==0) ? qo : ko;
      // q scale folds softmax 1/sqrt(d) AND log2(e) for exp2-softmax
      const float scale = (t==0) ? (0.17677669529663689f * 1.4426950408889634f) : 1.0f;
      int hoff[4]; float bvs[4];
#pragma unroll
      for (int tj=0; tj<4; ++tj){
        int colt = cb + tj*16;
        hoff[tj] = (colt>>5)*1568 + (colt&31) + l15; // head*49*32 + dd
        bvs[tj] = bias[by*128 + wc*64 + tj*16 + l15] * scale;
      }
#pragma unroll
      for (int ti=0; ti<4; ++ti){
#pragma unroll
        for (int r=0; r<4; ++r){
          int R = rbase + ti*16 + r;
          int win = R / 49, nn = R - win*49;
          size_t rowoff = (size_t)win*18816 + nn*32;
#pragma unroll
          for (int tj=0; tj<4; ++tj)
            Pout[rowoff + hoff[tj]] = f2bf(acc[ti][tj][r]*scale + bvs[tj]);
        }
      }
    } else {
      // V transposed: vo[(win*12+head)*1792 + dd*56 + nn]
      int voff[4]; float bvs[4];
#pragma unroll
      for (int tj=0; tj<4; ++tj){
        int col = cb + tj*16 + l15;
        voff[tj] = (col>>5)*1792 + (col&31)*56;
        bvs[tj] = bias[768 + col];
      }
#pragma unroll
      for (int ti=0; ti<4; ++ti){
#pragma unroll
        for (int r=0; r<4; ++r){
          int R = rbase + ti*16 + r;
          int win = R / 49, nn = R - win*49;
          size_t wb = (size_t)win*21504 + nn;
#pragma unroll
          for (int tj=0; tj<4; ++tj)
            vo[wb + voff[tj]] = f2bf(acc[ti][tj][r] + bvs[tj]);
        }
      }
    }
  } else {
    const int cbs = blockIdx.y*128 + wc*64;        // scalar col base
    float bv[4];
#pragma unroll
    for (int tj=0; tj<4; ++tj) bv[tj] = bias[cbs + tj*16 + l15];
#pragma unroll
    for (int ti=0; ti<4; ++ti){
#pragma unroll
      for (int r=0; r<4; ++r){
        int R = rbase + ti*16 + r;
        int win = R / 49, nn = R - win*49;
        int p = nn / 7, q = nn - p*7;
        int h = (win >> 3) & 7, w = win & 7;
        size_t tok = (size_t)(win >> 6)*3136 + (size_t)((p*8 + h)*56 + q*8 + w);
        float* __restrict__ orow = out + tok*384 + cbs + l15;
#pragma unroll
        for (int tj=0; tj<4; ++tj)
          orow[tj*16] = acc[ti][tj][r] + bv[tj];
      }
    }
  }
}

// ---- windowed attention, swapped-QK^T in-register softmax.
// 1 wave per (window, head). S^T = mfma(K,Q) with bias C-init (log2e-scaled,
// -inf mask k>=49); exp2, in-lane row sums (+2 shuffles); P*rinv packed via
// cvt_pk -> swizzled LDS b64; PV reads V^T [32][56] with vector loads. ----
__global__ __launch_bounds__(256) void attn_kernel(const unsigned short* __restrict__ q,
                                                   const unsigned short* __restrict__ k,
                                                   const unsigned short* __restrict__ vt,
                                                   const float* __restrict__ btab,
                                                   unsigned short* __restrict__ ao)
{
  __shared__ unsigned short P[4][4096];   // per-wave 64x64 bf16, XOR-swizzled
  const int tid = threadIdx.x, lane = tid & 63, wid = tid >> 6;
  const int l15 = lane & 15, kg = lane >> 4;
  const int win = blockIdx.x / 3;
  const int head = (blockIdx.x % 3)*4 + wid;
  const size_t base = ((size_t)win*12 + head)*1568;   // 49*32
  const unsigned short* qb = q + base;
  const unsigned short* kb = k + base;
  const unsigned short* vtb = vt + ((size_t)win*12 + head)*1792;
  const float* bt = btab + head*4096;

  // S^T C-init = bias fragment (row k = kg*4+r, col q = l15)
  f32x4 s[4][4];
#pragma unroll
  for (int ti=0; ti<4; ++ti)
#pragma unroll
    for (int tj=0; tj<4; ++tj)
      s[ti][tj] = *(const f32x4*)(bt + (tj*16 + l15)*64 + ti*16 + kg*4);

  bf16x8 kf[4], qf[4];
#pragma unroll
  for (int ti=0; ti<4; ++ti) kf[ti] = *(const bf16x8*)(kb + (ti*16+l15)*32 + kg*8);
#pragma unroll
  for (int tj=0; tj<4; ++tj) qf[tj] = *(const bf16x8*)(qb + (tj*16+l15)*32 + kg*8);

  __builtin_amdgcn_s_setprio(1);
#pragma unroll
  for (int ti=0; ti<4; ++ti)
#pragma unroll
    for (int tj=0; tj<4; ++tj)
      s[ti][tj] = __builtin_amdgcn_mfma_f32_16x16x32_bf16(kf[ti], qf[tj], s[ti][tj], 0,0,0);
  __builtin_amdgcn_s_setprio(0);

  // softmax: lane owns 4 q-rows (tj), 16 k-values each in-register.
  // exp2 (log2e pre-folded); no max-subtract (|s| bounded ~12, fp32-safe).
  float rinv[4];
#pragma unroll
  for (int tj=0; tj<4; ++tj){
    float sum = 0.f;
#pragma unroll
    for (int ti=0; ti<4; ++ti)
#pragma unroll
      for (int r=0; r<4; ++r){
        float e = exp2f(s[ti][tj][r]);
        s[ti][tj][r] = e;
        sum += e;
      }
    sum += __shfl_xor(sum, 16);
    sum += __shfl_xor(sum, 32);
    rinv[tj] = __builtin_amdgcn_rcpf(sum);
  }

  // pack P (x rinv) as bf16 k-pairs -> swizzled LDS [q=64][k=64]
  unsigned short* Pl = P[wid];
  const unsigned swz = (unsigned)((l15 & 7) << 4);
#pragma unroll
  for (int tj=0; tj<4; ++tj){
    const float rv = rinv[tj];
    const unsigned rowb = (unsigned)((tj*16 + l15)*128);
#pragma unroll
    for (int ti=0; ti<4; ++ti){
      uint2 d;
      d.x = cvt_pk_bf16(s[ti][tj][0]*rv, s[ti][tj][1]*rv);
      d.y = cvt_pk_bf16(s[ti][tj][2]*rv, s[ti][tj][3]*rv);
      unsigned boff = (rowb + (unsigned)(ti*32 + kg*8)) ^ swz;
      *(uint2*)((char*)Pl + boff) = d;
    }
  }

  // V^T B-fragments (vector 16B loads); mask nn>=49 in-register (NaN-safe)
  bf16x8 vtf[2][2];
#pragma unroll
  for (int tjv=0; tjv<2; ++tjv){
#pragma unroll
    for (int ks=0; ks<2; ++ks)
      vtf[tjv][ks] = *(const bf16x8*)(vtb + (tjv*16+l15)*56 + ks*32 + kg*8);
    uint4 u = *(uint4*)&vtf[tjv][1];           // ks=1: nn = 32+kg*8+e
    if (kg == 2){ u.x &= 0xFFFFu; u.y = 0; u.z = 0; u.w = 0; }   // keep nn=48 only
    else if (kg == 3){ u.x = 0; u.y = 0; u.z = 0; u.w = 0; }
    *(uint4*)&vtf[tjv][1] = u;
  }

  // O = P @ V^T-rows
  f32x4 o[4][2] = {};
#pragma unroll
  for (int oti=0; oti<4; ++oti){
    bf16x8 pa[2];
#pragma unroll
    for (int ks=0; ks<2; ++ks){
      unsigned boff = ((unsigned)((oti*16+l15)*128 + ks*64 + kg*16)) ^ swz;
      pa[ks] = *(const bf16x8*)((char*)Pl + boff);
    }
    __builtin_amdgcn_s_setprio(1);
#pragma unroll
    for (int tjv=0; tjv<2; ++tjv){
      o[oti][tjv] = __builtin_amdgcn_mfma_f32_16x16x32_bf16(pa[0], vtf[tjv][0], o[oti][tjv], 0,0,0);
      o[oti][tjv] = __builtin_amdgcn_mfma_f32_16x16x32_bf16(pa[1], vtf[tjv][1], o[oti][tjv], 0,0,0);
    }
    __builtin_amdgcn_s_setprio(0);
  }

  // store rows < 49 (rinv already folded into P)
#pragma unroll
  for (int oti=0; oti<4; ++oti)
#pragma unroll
    for (int r=0; r<4; ++r){
      int row = oti*16 + kg*4 + r;
      if (row < 49){
        unsigned short* op = ao + ((size_t)win*49 + row)*384 + head*32 + l15;
        op[0]  = (unsigned short)cvt_pk_bf16(o[oti][0][r], o[oti][0][r]);
        op[16] = (unsigned short)cvt_pk_bf16(o[oti][1][r], o[oti][1][r]);
      }
    }
}

extern "C" void kernel_launch(void* const* d_in, const int* in_sizes, int n_in,
                              void* d_out, int out_size, void* d_ws, size_t ws_size,
                              hipStream_t stream)
{
  const float* x       = (const float*)d_in[0];   // 32*56*56*384
  const float* w_qkv   = (const float*)d_in[1];   // 1152*384
  const float* b_qkv   = (const float*)d_in[2];   // 1152
  const float* rel_pos = (const float*)d_in[3];   // 12*169
  const float* w_out   = (const float*)d_in[4];   // 384*384
  const float* b_out   = (const float*)d_in[5];   // 384
  float* out = (float*)d_out;                     // 100352*384

  char* ws = (char*)d_ws;
  unsigned short* wqb = (unsigned short*)ws;                  // 884736 B
  unsigned short* wob = (unsigned short*)(ws + 884736);       // 294912 B
  float* btab         = (float*)(ws + 884736 + 294912);       // 196608 B
  unsigned short* qws = (unsigned short*)(ws + 1376256);      // 38535168 elems
  unsigned short* kws = qws + 38535168;                       // 38535168 elems
  unsigned short* vtw = kws + 38535168;                       // 44040256 elems (24576*1792 + pad)
  unsigned short* xb  = vtw + 44040256;   // x_bf during GEMM1, attn-out after
  unsigned short* ao  = xb;               // total ws use ~320.7 MB

  convert_x_kernel<<<dim3(37632), dim3(256), 0, stream>>>(x, xb);
  convert_w_kernel<<<dim3(576),   dim3(256), 0, stream>>>(w_qkv, w_out, wqb, wob);
  build_btab<<<dim3(192), dim3(256), 0, stream>>>(rel_pos, btab);
  gemm128<0><<<dim3(784, 9), dim3(256), 0, stream>>>(xb, wqb, b_qkv, qws, kws, vtw, nullptr);
  attn_kernel<<<dim3(6144), dim3(256), 0, stream>>>(qws, kws, vtw, btab, ao);
  gemm128<1><<<dim3(784, 3), dim3(256), 0, stream>>>(ao, wob, b_out, nullptr, nullptr, nullptr, out);
}

// Round 4
// 348.784 us; speedup vs baseline: 1.1921x; 1.1921x over previous
//
#include <hip/hip_runtime.h>

typedef __attribute__((ext_vector_type(8))) short bf16x8;
typedef __attribute__((ext_vector_type(4))) float f32x4;

__device__ __forceinline__ unsigned short f2bf(float f){
  unsigned u = __builtin_bit_cast(unsigned, f);
  u += 0x7fffu + ((u >> 16) & 1u);
  return (unsigned short)(u >> 16);
}

__device__ __forceinline__ unsigned cvt_pk_bf16(float lo, float hi){
  unsigned r;
  asm("v_cvt_pk_bf16_f32 %0, %1, %2" : "=v"(r) : "v"(lo), "v"(hi));
  return r;
}

#define ASYNC16(ldsp, gp) __builtin_amdgcn_global_load_lds( \
    (const __attribute__((address_space(1))) unsigned int*)(gp), \
    (__attribute__((address_space(3))) unsigned int*)(ldsp), 16, 0, 0)

// ---- convert x (fp32 [b,56,56,384]) -> bf16 window-ordered [win*49+n][384] ----
__global__ __launch_bounds__(256) void convert_x_kernel(const float* __restrict__ x,
                                                        unsigned short* __restrict__ xb){
  int idx = blockIdx.x*256 + threadIdx.x;          // 100352*96 threads, 4 ch each
  int token = idx / 96, j = idx - token*96;
  int b = token / 3136, rem = token - b*3136;
  int rr = rem / 56, cp = rem - rr*56;
  int p = rr >> 3, h = rr & 7, q = cp >> 3, w = cp & 7;
  int orow = ((b*8 + h)*8 + w)*49 + p*7 + q;
  float4 v = *(const float4*)(x + (size_t)idx*4);
  ushort4 o;
  o.x = f2bf(v.x); o.y = f2bf(v.y); o.z = f2bf(v.z); o.w = f2bf(v.w);
  *(ushort4*)(xb + (size_t)orow*384 + j*4) = o;
}

// ---- convert weights fp32 -> bf16 ----
__global__ __launch_bounds__(256) void convert_w_kernel(const float* __restrict__ wq,
                                                        const float* __restrict__ wo,
                                                        unsigned short* __restrict__ wqb,
                                                        unsigned short* __restrict__ wob){
  int idx = blockIdx.x*256 + threadIdx.x;          // 147456 threads
  if (idx < 110592){
    float4 v = *(const float4*)(wq + (size_t)idx*4);
    ushort4 o; o.x=f2bf(v.x); o.y=f2bf(v.y); o.z=f2bf(v.z); o.w=f2bf(v.w);
    *(ushort4*)(wqb + (size_t)idx*4) = o;
  } else {
    int k = idx - 110592;
    float4 v = *(const float4*)(wo + (size_t)k*4);
    ushort4 o; o.x=f2bf(v.x); o.y=f2bf(v.y); o.z=f2bf(v.z); o.w=f2bf(v.w);
    *(ushort4*)(wob + (size_t)k*4) = o;
  }
}

// ---- bias table, FRAGMENT-major: btab[head][fi=ti*4+tj][lane][r] (f32),
// log2(e)-pre-scaled; -inf for k>=49 (mask); 0 for q>=49. Coalesced b128 loads. ----
__global__ __launch_bounds__(256) void build_btab(const float* __restrict__ rel_pos,
                                                  float* __restrict__ btab){
  int idx = blockIdx.x*256 + threadIdx.x;          // 12288 threads
  int head = idx >> 10, rem = idx & 1023;
  int fi = rem >> 6, lane = rem & 63;
  int ti = fi >> 2, tj = fi & 3;
  int qq = tj*16 + (lane & 15);
  int kb = ti*16 + (lane >> 4)*4;
  float4 v; float* vp = (float*)&v;
#pragma unroll
  for (int r=0; r<4; ++r){
    int kk = kb + r;
    float val;
    if (kk >= 49) val = -__builtin_inff();
    else if (qq >= 49) val = 0.f;
    else {
      int ip = qq/7, iq = qq - ip*7, jp = kk/7, jq = kk - jp*7;
      val = rel_pos[head*169 + (ip-jp+6)*13 + (iq-jq+6)] * 1.4426950408889634f;
    }
    vp[r] = val;
  }
  *(float4*)(btab + (size_t)idx*4) = v;
}

// ---- 128x128 tile bf16 GEMM, C = A @ B^T + bias, K=384 fixed.
// Quad-buffered single-barrier pipeline, counted vmcnt(8), XOR k-chunk swizzle
// (pre-swizzled global source + swizzled ds_read: 2-way banks = free).
// EPI 0: q(*scale*log2e)/k/v bf16 [win][head][49][32].  EPI 1: fp32 un-windowed.
template<int EPI>
__global__ __launch_bounds__(256) void gemm128(const unsigned short* __restrict__ A,
                                               const unsigned short* __restrict__ B,
                                               const float* __restrict__ bias,
                                               unsigned short* __restrict__ qo,
                                               unsigned short* __restrict__ ko,
                                               unsigned short* __restrict__ vo,
                                               float* __restrict__ out)
{
  constexpr int K = 384;
  constexpr int NT = 12;                    // K/32
  __shared__ unsigned short Al[4][128*32];
  __shared__ unsigned short Bl[4][128*32];
  const int tid = threadIdx.x;
  const int lane = tid & 63, wid = tid >> 6;
  const int wr = wid >> 1, wc = wid & 1;
  const int l15 = lane & 15, kg = lane >> 4;
  const int swz = (l15 >> 1) & 3;                       // read-side chunk XOR
  const int cswz = (tid & 3) ^ ((tid >> 3) & 3);        // source pre-swizzle

  const unsigned short* Ag = A + ((size_t)blockIdx.x*128 + (tid>>2))*K + cswz*8;
  const unsigned short* Bg = B + ((size_t)blockIdx.y*128 + (tid>>2))*K + cswz*8;

  f32x4 acc[4][4] = {};

#define STAGE(buf, kt) do { \
    ASYNC16(&Al[buf][wid*512],        Ag + (kt)*32); \
    ASYNC16(&Al[buf][wid*512 + 2048], Ag + (size_t)64*K + (kt)*32); \
    ASYNC16(&Bl[buf][wid*512],        Bg + (kt)*32); \
    ASYNC16(&Bl[buf][wid*512 + 2048], Bg + (size_t)64*K + (kt)*32); \
  } while(0)

  STAGE(0,0); STAGE(1,1); STAGE(2,2);       // 12 loads in flight

#pragma unroll
  for (int t = 0; t < NT; ++t){
    // own loads of tile t done; barrier publishes all waves' loads AND
    // proves all waves finished iter t-1 (so b[(t+3)&3]=b[(t-1)&3] is free).
    if (t < 10)       asm volatile("s_waitcnt vmcnt(8)\n\ts_barrier" ::: "memory");
    else if (t == 10) asm volatile("s_waitcnt vmcnt(4)\n\ts_barrier" ::: "memory");
    else              asm volatile("s_waitcnt vmcnt(0)\n\ts_barrier" ::: "memory");

    if (t + 3 < NT) STAGE((t+3)&3, t+3);

    const unsigned short* Ab = Al[t & 3];
    const unsigned short* Bb = Bl[t & 3];
    bf16x8 af[4], bfv[4];
#pragma unroll
    for (int ti=0; ti<4; ++ti)
      af[ti] = *(const bf16x8*)(Ab + (wr*64 + ti*16 + l15)*32 + (kg ^ swz)*8);
#pragma unroll
    for (int tj=0; tj<4; ++tj)
      bfv[tj] = *(const bf16x8*)(Bb + (wc*64 + tj*16 + l15)*32 + (kg ^ swz)*8);

    __builtin_amdgcn_s_setprio(1);
#pragma unroll
    for (int ti=0; ti<4; ++ti)
#pragma unroll
      for (int tj=0; tj<4; ++tj)
        acc[ti][tj] = __builtin_amdgcn_mfma_f32_16x16x32_bf16(af[ti], bfv[tj], acc[ti][tj], 0,0,0);
    __builtin_amdgcn_s_setprio(0);
  }
#undef STAGE

  const int rbase = blockIdx.x*128 + wr*64 + kg*4;

  if (EPI == 0){
    const int by = blockIdx.y;
    const int t = by / 3;                          // block-uniform q/k/v select
    unsigned short* __restrict__ Pout = (t==0) ? qo : ((t==1) ? ko : vo);
    // q scale folds softmax 1/sqrt(d) AND log2(e) for exp2-softmax
    const float scale = (t==0) ? (0.17677669529663689f * 1.4426950408889634f) : 1.0f;
    const int cb = (by - t*3)*128 + wc*64;         // col base within 384
    int hoff[4]; float bvs[4];
#pragma unroll
    for (int tj=0; tj<4; ++tj){
      int colt = cb + tj*16;
      hoff[tj] = (colt>>5)*1568 + (colt&31) + l15; // head*49*32 + dd
      bvs[tj] = bias[by*128 + wc*64 + tj*16 + l15] * scale;
    }
#pragma unroll
    for (int ti=0; ti<4; ++ti){
#pragma unroll
      for (int r=0; r<4; ++r){
        int R = rbase + ti*16 + r;
        int win = R / 49, nn = R - win*49;
        size_t rowoff = (size_t)win*18816 + nn*32;
#pragma unroll
        for (int tj=0; tj<4; ++tj)
          Pout[rowoff + hoff[tj]] = f2bf(acc[ti][tj][r]*scale + bvs[tj]);
      }
    }
  } else {
    const int cbs = blockIdx.y*128 + wc*64;        // scalar col base
    float bv[4];
#pragma unroll
    for (int tj=0; tj<4; ++tj) bv[tj] = bias[cbs + tj*16 + l15];
#pragma unroll
    for (int ti=0; ti<4; ++ti){
#pragma unroll
      for (int r=0; r<4; ++r){
        int R = rbase + ti*16 + r;
        int win = R / 49, nn = R - win*49;
        int p = nn / 7, q = nn - p*7;
        int h = (win >> 3) & 7, w = win & 7;
        size_t tok = (size_t)(win >> 6)*3136 + (size_t)((p*8 + h)*56 + q*8 + w);
        float* __restrict__ orow = out + tok*384 + cbs + l15;
#pragma unroll
        for (int tj=0; tj<4; ++tj)
          orow[tj*16] = acc[ti][tj][r] + bv[tj];
      }
    }
  }
}

// ---- windowed attention, swapped-QK^T in-register softmax.
// 1 wave per (window, head). Bias C-init from fragment-major btab (coalesced);
// exp2 softmax, in-lane row sums (+2 shuffles); P*rinv via cvt_pk -> swizzled
// LDS b64; V row-major, fragments loaded early as scalars (latency hidden). ----
__global__ __launch_bounds__(256) void attn_kernel(const unsigned short* __restrict__ q,
                                                   const unsigned short* __restrict__ k,
                                                   const unsigned short* __restrict__ v,
                                                   const float* __restrict__ btab,
                                                   unsigned short* __restrict__ ao)
{
  __shared__ unsigned short P[4][4096];   // per-wave 64x64 bf16, XOR-swizzled
  const int tid = threadIdx.x, lane = tid & 63, wid = tid >> 6;
  const int l15 = lane & 15, kg = lane >> 4;
  const int win = blockIdx.x / 3;
  const int head = (blockIdx.x % 3)*4 + wid;
  const size_t base = ((size_t)win*12 + head)*1568;   // 49*32
  const unsigned short* qb = q + base;
  const unsigned short* kb = k + base;
  const unsigned short* vb = v + base;
  const float* bt = btab + head*4096;

  // V fragments first (independent; latency hides under QK^T + softmax).
  // Rows >=49 read neighbor data (finite bf16) and are multiplied by P==0.
  bf16x8 vfk[2][2];
#pragma unroll
  for (int ks=0; ks<2; ++ks)
#pragma unroll
    for (int tjv=0; tjv<2; ++tjv)
#pragma unroll
      for (int e=0; e<8; ++e)
        vfk[ks][tjv][e] = (short)vb[(ks*32 + kg*8 + e)*32 + tjv*16 + l15];

  // S^T C-init = bias fragment (coalesced b128 per frag)
  f32x4 s[4][4];
#pragma unroll
  for (int ti=0; ti<4; ++ti)
#pragma unroll
    for (int tj=0; tj<4; ++tj)
      s[ti][tj] = *(const f32x4*)(bt + ((ti*4 + tj)*64 + lane)*4);

  bf16x8 kf[4], qf[4];
#pragma unroll
  for (int ti=0; ti<4; ++ti) kf[ti] = *(const bf16x8*)(kb + (ti*16+l15)*32 + kg*8);
#pragma unroll
  for (int tj=0; tj<4; ++tj) qf[tj] = *(const bf16x8*)(qb + (tj*16+l15)*32 + kg*8);

  __builtin_amdgcn_s_setprio(1);
#pragma unroll
  for (int ti=0; ti<4; ++ti)
#pragma unroll
    for (int tj=0; tj<4; ++tj)
      s[ti][tj] = __builtin_amdgcn_mfma_f32_16x16x32_bf16(kf[ti], qf[tj], s[ti][tj], 0,0,0);
  __builtin_amdgcn_s_setprio(0);

  // softmax: lane owns 4 q-rows (tj), 16 k-values each in-register.
  float rinv[4];
#pragma unroll
  for (int tj=0; tj<4; ++tj){
    float sum = 0.f;
#pragma unroll
    for (int ti=0; ti<4; ++ti)
#pragma unroll
      for (int r=0; r<4; ++r){
        float e = exp2f(s[ti][tj][r]);
        s[ti][tj][r] = e;
        sum += e;
      }
    sum += __shfl_xor(sum, 16);
    sum += __shfl_xor(sum, 32);
    rinv[tj] = __builtin_amdgcn_rcpf(sum);
  }

  // pack P (x rinv) as bf16 k-pairs -> swizzled LDS [q=64][k=64]
  unsigned short* Pl = P[wid];
  const unsigned swz = (unsigned)((l15 & 7) << 4);
#pragma unroll
  for (int tj=0; tj<4; ++tj){
    const float rv = rinv[tj];
    const unsigned rowb = (unsigned)((tj*16 + l15)*128);
#pragma unroll
    for (int ti=0; ti<4; ++ti){
      uint2 d;
      d.x = cvt_pk_bf16(s[ti][tj][0]*rv, s[ti][tj][1]*rv);
      d.y = cvt_pk_bf16(s[ti][tj][2]*rv, s[ti][tj][3]*rv);
      unsigned boff = (rowb + (unsigned)(ti*32 + kg*8)) ^ swz;
      *(uint2*)((char*)Pl + boff) = d;
    }
  }

  // O = P @ V
  f32x4 o[4][2] = {};
#pragma unroll
  for (int oti=0; oti<4; ++oti){
    bf16x8 pa[2];
#pragma unroll
    for (int ks=0; ks<2; ++ks){
      unsigned boff = ((unsigned)((oti*16+l15)*128 + ks*64 + kg*16)) ^ swz;
      pa[ks] = *(const bf16x8*)((char*)Pl + boff);
    }
    __builtin_amdgcn_s_setprio(1);
#pragma unroll
    for (int tjv=0; tjv<2; ++tjv){
      o[oti][tjv] = __builtin_amdgcn_mfma_f32_16x16x32_bf16(pa[0], vfk[0][tjv], o[oti][tjv], 0,0,0);
      o[oti][tjv] = __builtin_amdgcn_mfma_f32_16x16x32_bf16(pa[1], vfk[1][tjv], o[oti][tjv], 0,0,0);
    }
    __builtin_amdgcn_s_setprio(0);
  }

  // store rows < 49 (rinv already folded into P)
#pragma unroll
  for (int oti=0; oti<4; ++oti)
#pragma unroll
    for (int r=0; r<4; ++r){
      int row = oti*16 + kg*4 + r;
      if (row < 49){
        unsigned short* op = ao + ((size_t)win*49 + row)*384 + head*32 + l15;
        op[0]  = (unsigned short)cvt_pk_bf16(o[oti][0][r], o[oti][0][r]);
        op[16] = (unsigned short)cvt_pk_bf16(o[oti][1][r], o[oti][1][r]);
      }
    }
}

extern "C" void kernel_launch(void* const* d_in, const int* in_sizes, int n_in,
                              void* d_out, int out_size, void* d_ws, size_t ws_size,
                              hipStream_t stream)
{
  const float* x       = (const float*)d_in[0];   // 32*56*56*384
  const float* w_qkv   = (const float*)d_in[1];   // 1152*384
  const float* b_qkv   = (const float*)d_in[2];   // 1152
  const float* rel_pos = (const float*)d_in[3];   // 12*169
  const float* w_out   = (const float*)d_in[4];   // 384*384
  const float* b_out   = (const float*)d_in[5];   // 384
  float* out = (float*)d_out;                     // 100352*384

  char* ws = (char*)d_ws;
  unsigned short* wqb = (unsigned short*)ws;                  // 884736 B
  unsigned short* wob = (unsigned short*)(ws + 884736);       // 294912 B
  float* btab         = (float*)(ws + 884736 + 294912);       // 196608 B
  unsigned short* qws = (unsigned short*)(ws + 1376256);      // 38535168 elems
  unsigned short* kws = qws + 38535168;
  unsigned short* vws = kws + 38535168;
  unsigned short* xb  = vws + 38535168;   // x_bf during GEMM1, attn-out after
  unsigned short* ao  = xb;               // total ws ~309.7 MB

  convert_x_kernel<<<dim3(37632), dim3(256), 0, stream>>>(x, xb);
  convert_w_kernel<<<dim3(576),   dim3(256), 0, stream>>>(w_qkv, w_out, wqb, wob);
  build_btab<<<dim3(48), dim3(256), 0, stream>>>(rel_pos, btab);
  gemm128<0><<<dim3(784, 9), dim3(256), 0, stream>>>(xb, wqb, b_qkv, qws, kws, vws, nullptr);
  attn_kernel<<<dim3(6144), dim3(256), 0, stream>>>(qws, kws, vws, btab, ao);
  gemm128<1><<<dim3(784, 3), dim3(256), 0, stream>>>(ao, wob, b_out, nullptr, nullptr, nullptr, out);
}

// Round 5
// 309.615 us; speedup vs baseline: 1.3430x; 1.1265x over previous
//
#include <hip/hip_runtime.h>

typedef __attribute__((ext_vector_type(8))) short bf16x8;
typedef __attribute__((ext_vector_type(4))) float f32x4;

__device__ __forceinline__ unsigned short f2bf(float f){
  unsigned u = __builtin_bit_cast(unsigned, f);
  u += 0x7fffu + ((u >> 16) & 1u);
  return (unsigned short)(u >> 16);
}

__device__ __forceinline__ unsigned cvt_pk_bf16(float lo, float hi){
  unsigned r;
  asm("v_cvt_pk_bf16_f32 %0, %1, %2" : "=v"(r) : "v"(lo), "v"(hi));
  return r;
}

#define ASYNC16(ldsp, gp) __builtin_amdgcn_global_load_lds( \
    (const __attribute__((address_space(1))) unsigned int*)(gp), \
    (__attribute__((address_space(3))) unsigned int*)(ldsp), 16, 0, 0)

// ---- convert x (fp32 [b,56,56,384]) -> bf16 window-ordered [win*49+n][384] ----
__global__ __launch_bounds__(256) void convert_x_kernel(const float* __restrict__ x,
                                                        unsigned short* __restrict__ xb){
  int idx = blockIdx.x*256 + threadIdx.x;          // 100352*96 threads, 4 ch each
  int token = idx / 96, j = idx - token*96;
  int b = token / 3136, rem = token - b*3136;
  int rr = rem / 56, cp = rem - rr*56;
  int p = rr >> 3, h = rr & 7, q = cp >> 3, w = cp & 7;
  int orow = ((b*8 + h)*8 + w)*49 + p*7 + q;
  float4 v = *(const float4*)(x + (size_t)idx*4);
  ushort4 o;
  o.x = f2bf(v.x); o.y = f2bf(v.y); o.z = f2bf(v.z); o.w = f2bf(v.w);
  *(ushort4*)(xb + (size_t)orow*384 + j*4) = o;
}

// ---- convert weights fp32 -> bf16 ----
__global__ __launch_bounds__(256) void convert_w_kernel(const float* __restrict__ wq,
                                                        const float* __restrict__ wo,
                                                        unsigned short* __restrict__ wqb,
                                                        unsigned short* __restrict__ wob){
  int idx = blockIdx.x*256 + threadIdx.x;          // 147456 threads
  if (idx < 110592){
    float4 v = *(const float4*)(wq + (size_t)idx*4);
    ushort4 o; o.x=f2bf(v.x); o.y=f2bf(v.y); o.z=f2bf(v.z); o.w=f2bf(v.w);
    *(ushort4*)(wqb + (size_t)idx*4) = o;
  } else {
    int k = idx - 110592;
    float4 v = *(const float4*)(wo + (size_t)k*4);
    ushort4 o; o.x=f2bf(v.x); o.y=f2bf(v.y); o.z=f2bf(v.z); o.w=f2bf(v.w);
    *(ushort4*)(wob + (size_t)k*4) = o;
  }
}

// ---- bias table, FRAGMENT-major: btab[head][fi=ti*4+tj][lane][r] (f32),
// log2(e)-pre-scaled; -inf for k>=49 (mask); 0 for q>=49. Coalesced b128 loads. ----
__global__ __launch_bounds__(256) void build_btab(const float* __restrict__ rel_pos,
                                                  float* __restrict__ btab){
  int idx = blockIdx.x*256 + threadIdx.x;          // 12288 threads
  int head = idx >> 10, rem = idx & 1023;
  int fi = rem >> 6, lane = rem & 63;
  int ti = fi >> 2, tj = fi & 3;
  int qq = tj*16 + (lane & 15);
  int kb = ti*16 + (lane >> 4)*4;
  float4 v; float* vp = (float*)&v;
#pragma unroll
  for (int r=0; r<4; ++r){
    int kk = kb + r;
    float val;
    if (kk >= 49) val = -__builtin_inff();
    else if (qq >= 49) val = 0.f;
    else {
      int ip = qq/7, iq = qq - ip*7, jp = kk/7, jq = kk - jp*7;
      val = rel_pos[head*169 + (ip-jp+6)*13 + (iq-jq+6)] * 1.4426950408889634f;
    }
    vp[r] = val;
  }
  *(float4*)(btab + (size_t)idx*4) = v;
}

// ---- 128x128 tile bf16 GEMM, C = A @ B^T + bias, K=384 fixed, M=100352.
// Triple-buffered single-barrier pipeline, counted vmcnt(4), XOR k-chunk swizzle.
// Same-XCD A-panel block swizzle: the NBY blocks sharing one A-panel run
// temporally adjacent on one XCD -> 1 L2 fill + NBY-1 hits.
// EPI 0: q(*scale*log2e)/k/v bf16 [win][head][49][32].  EPI 1: fp32 un-windowed.
template<int EPI, int NBY>
__global__ __launch_bounds__(256) void gemm128(const unsigned short* __restrict__ A,
                                               const unsigned short* __restrict__ B,
                                               const float* __restrict__ bias,
                                               unsigned short* __restrict__ qo,
                                               unsigned short* __restrict__ ko,
                                               unsigned short* __restrict__ vo,
                                               float* __restrict__ out)
{
  constexpr int K = 384;
  constexpr int NT = 12;                    // K/32
  __shared__ unsigned short Al[3][128*32];
  __shared__ unsigned short Bl[3][128*32];
  const int tid = threadIdx.x;
  const int lane = tid & 63, wid = tid >> 6;
  const int wr = wid >> 1, wc = wid & 1;
  const int l15 = lane & 15, kg = lane >> 4;
  const int swz = (l15 >> 1) & 3;                       // read-side chunk XOR
  const int cswz = (tid & 3) ^ ((tid >> 3) & 3);        // source pre-swizzle

  // block swizzle: 784 = 98*8 panels, NBY n-blocks per panel stay on one XCD
  const int n = blockIdx.x;
  const int xcd = n & 7, s = n >> 3;
  const int panel = s / NBY, nb = s - panel*NBY;
  const int bx = panel*8 + xcd, by = nb;

  const unsigned short* Ag = A + ((size_t)bx*128 + (tid>>2))*K + cswz*8;
  const unsigned short* Bg = B + ((size_t)by*128 + (tid>>2))*K + cswz*8;

  f32x4 acc[4][4] = {};

#define STAGE(buf, kt) do { \
    ASYNC16(&Al[buf][wid*512],        Ag + (kt)*32); \
    ASYNC16(&Al[buf][wid*512 + 2048], Ag + (size_t)64*K + (kt)*32); \
    ASYNC16(&Bl[buf][wid*512],        Bg + (kt)*32); \
    ASYNC16(&Bl[buf][wid*512 + 2048], Bg + (size_t)64*K + (kt)*32); \
  } while(0)

  STAGE(0,0); STAGE(1,1);                   // 8 loads in flight

#pragma unroll
  for (int t = 0; t < NT; ++t){
    // own loads of tile t done (4 of t+1 may stay in flight); barrier
    // publishes all waves' tile-t loads AND proves all waves finished
    // reading the buffer staged below (freed at iter t-1).
    if (t < NT-1) asm volatile("s_waitcnt vmcnt(4)\n\ts_barrier" ::: "memory");
    else          asm volatile("s_waitcnt vmcnt(0)\n\ts_barrier" ::: "memory");

    if (t + 2 < NT) STAGE((t+2)%3, t+2);

    const unsigned short* Ab = Al[t % 3];
    const unsigned short* Bb = Bl[t % 3];
    bf16x8 af[4], bfv[4];
#pragma unroll
    for (int ti=0; ti<4; ++ti)
      af[ti] = *(const bf16x8*)(Ab + (wr*64 + ti*16 + l15)*32 + (kg ^ swz)*8);
#pragma unroll
    for (int tj=0; tj<4; ++tj)
      bfv[tj] = *(const bf16x8*)(Bb + (wc*64 + tj*16 + l15)*32 + (kg ^ swz)*8);

    __builtin_amdgcn_s_setprio(1);
#pragma unroll
    for (int ti=0; ti<4; ++ti)
#pragma unroll
      for (int tj=0; tj<4; ++tj)
        acc[ti][tj] = __builtin_amdgcn_mfma_f32_16x16x32_bf16(af[ti], bfv[tj], acc[ti][tj], 0,0,0);
    __builtin_amdgcn_s_setprio(0);
  }
#undef STAGE

  const int rbase = bx*128 + wr*64 + kg*4;

  if (EPI == 0){
    const int t = by / 3;                          // block-uniform q/k/v select
    unsigned short* __restrict__ Pout = (t==0) ? qo : ((t==1) ? ko : vo);
    // q scale folds softmax 1/sqrt(d) AND log2(e) for exp2-softmax
    const float scale = (t==0) ? (0.17677669529663689f * 1.4426950408889634f) : 1.0f;
    const int cb = (by - t*3)*128 + wc*64;         // col base within 384
    int hoff[4]; float bvs[4];
#pragma unroll
    for (int tj=0; tj<4; ++tj){
      int colt = cb + tj*16;
      hoff[tj] = (colt>>5)*1568 + (colt&31) + l15; // head*49*32 + dd
      bvs[tj] = bias[by*128 + wc*64 + tj*16 + l15] * scale;
    }
#pragma unroll
    for (int ti=0; ti<4; ++ti){
#pragma unroll
      for (int r=0; r<4; ++r){
        int R = rbase + ti*16 + r;
        int win = R / 49, nn = R - win*49;
        size_t rowoff = (size_t)win*18816 + nn*32;
#pragma unroll
        for (int tj=0; tj<4; ++tj)
          Pout[rowoff + hoff[tj]] = f2bf(acc[ti][tj][r]*scale + bvs[tj]);
      }
    }
  } else {
    const int cbs = by*128 + wc*64;                // scalar col base
    float bv[4];
#pragma unroll
    for (int tj=0; tj<4; ++tj) bv[tj] = bias[cbs + tj*16 + l15];
#pragma unroll
    for (int ti=0; ti<4; ++ti){
#pragma unroll
      for (int r=0; r<4; ++r){
        int R = rbase + ti*16 + r;
        int win = R / 49, nn = R - win*49;
        int p = nn / 7, q = nn - p*7;
        int h = (win >> 3) & 7, w = win & 7;
        size_t tok = (size_t)(win >> 6)*3136 + (size_t)((p*8 + h)*56 + q*8 + w);
        float* __restrict__ orow = out + tok*384 + cbs + l15;
#pragma unroll
        for (int tj=0; tj<4; ++tj)
          orow[tj*16] = acc[ti][tj][r] + bv[tj];
      }
    }
  }
}

// ---- windowed attention, swapped-QK^T in-register softmax.
// 1 wave per (window, head). Bias C-init from fragment-major btab (coalesced);
// exp2 softmax, in-lane row sums (+2 shuffles); P*rinv via cvt_pk -> swizzled
// LDS b64; V row-major, fragments loaded early as scalars (latency hidden). ----
__global__ __launch_bounds__(256) void attn_kernel(const unsigned short* __restrict__ q,
                                                   const unsigned short* __restrict__ k,
                                                   const unsigned short* __restrict__ v,
                                                   const float* __restrict__ btab,
                                                   unsigned short* __restrict__ ao)
{
  __shared__ unsigned short P[4][4096];   // per-wave 64x64 bf16, XOR-swizzled
  const int tid = threadIdx.x, lane = tid & 63, wid = tid >> 6;
  const int l15 = lane & 15, kg = lane >> 4;
  const int win = blockIdx.x / 3;
  const int head = (blockIdx.x % 3)*4 + wid;
  const size_t base = ((size_t)win*12 + head)*1568;   // 49*32
  const unsigned short* qb = q + base;
  const unsigned short* kb = k + base;
  const unsigned short* vb = v + base;
  const float* bt = btab + head*4096;

  // V fragments first (independent; latency hides under QK^T + softmax).
  // Rows >=49 read neighbor data (finite bf16) and are multiplied by P==0.
  bf16x8 vfk[2][2];
#pragma unroll
  for (int ks=0; ks<2; ++ks)
#pragma unroll
    for (int tjv=0; tjv<2; ++tjv)
#pragma unroll
      for (int e=0; e<8; ++e)
        vfk[ks][tjv][e] = (short)vb[(ks*32 + kg*8 + e)*32 + tjv*16 + l15];

  // S^T C-init = bias fragment (coalesced b128 per frag)
  f32x4 s[4][4];
#pragma unroll
  for (int ti=0; ti<4; ++ti)
#pragma unroll
    for (int tj=0; tj<4; ++tj)
      s[ti][tj] = *(const f32x4*)(bt + ((ti*4 + tj)*64 + lane)*4);

  bf16x8 kf[4], qf[4];
#pragma unroll
  for (int ti=0; ti<4; ++ti) kf[ti] = *(const bf16x8*)(kb + (ti*16+l15)*32 + kg*8);
#pragma unroll
  for (int tj=0; tj<4; ++tj) qf[tj] = *(const bf16x8*)(qb + (tj*16+l15)*32 + kg*8);

  __builtin_amdgcn_s_setprio(1);
#pragma unroll
  for (int ti=0; ti<4; ++ti)
#pragma unroll
    for (int tj=0; tj<4; ++tj)
      s[ti][tj] = __builtin_amdgcn_mfma_f32_16x16x32_bf16(kf[ti], qf[tj], s[ti][tj], 0,0,0);
  __builtin_amdgcn_s_setprio(0);

  // softmax: lane owns 4 q-rows (tj), 16 k-values each in-register.
  float rinv[4];
#pragma unroll
  for (int tj=0; tj<4; ++tj){
    float sum = 0.f;
#pragma unroll
    for (int ti=0; ti<4; ++ti)
#pragma unroll
      for (int r=0; r<4; ++r){
        float e = exp2f(s[ti][tj][r]);
        s[ti][tj][r] = e;
        sum += e;
      }
    sum += __shfl_xor(sum, 16);
    sum += __shfl_xor(sum, 32);
    rinv[tj] = __builtin_amdgcn_rcpf(sum);
  }

  // pack P (x rinv) as bf16 k-pairs -> swizzled LDS [q=64][k=64]
  unsigned short* Pl = P[wid];
  const unsigned swz = (unsigned)((l15 & 7) << 4);
#pragma unroll
  for (int tj=0; tj<4; ++tj){
    const float rv = rinv[tj];
    const unsigned rowb = (unsigned)((tj*16 + l15)*128);
#pragma unroll
    for (int ti=0; ti<4; ++ti){
      uint2 d;
      d.x = cvt_pk_bf16(s[ti][tj][0]*rv, s[ti][tj][1]*rv);
      d.y = cvt_pk_bf16(s[ti][tj][2]*rv, s[ti][tj][3]*rv);
      unsigned boff = (rowb + (unsigned)(ti*32 + kg*8)) ^ swz;
      *(uint2*)((char*)Pl + boff) = d;
    }
  }

  // O = P @ V
  f32x4 o[4][2] = {};
#pragma unroll
  for (int oti=0; oti<4; ++oti){
    bf16x8 pa[2];
#pragma unroll
    for (int ks=0; ks<2; ++ks){
      unsigned boff = ((unsigned)((oti*16+l15)*128 + ks*64 + kg*16)) ^ swz;
      pa[ks] = *(const bf16x8*)((char*)Pl + boff);
    }
    __builtin_amdgcn_s_setprio(1);
#pragma unroll
    for (int tjv=0; tjv<2; ++tjv){
      o[oti][tjv] = __builtin_amdgcn_mfma_f32_16x16x32_bf16(pa[0], vfk[0][tjv], o[oti][tjv], 0,0,0);
      o[oti][tjv] = __builtin_amdgcn_mfma_f32_16x16x32_bf16(pa[1], vfk[1][tjv], o[oti][tjv], 0,0,0);
    }
    __builtin_amdgcn_s_setprio(0);
  }

  // store rows < 49 (rinv already folded into P)
#pragma unroll
  for (int oti=0; oti<4; ++oti)
#pragma unroll
    for (int r=0; r<4; ++r){
      int row = oti*16 + kg*4 + r;
      if (row < 49){
        unsigned short* op = ao + ((size_t)win*49 + row)*384 + head*32 + l15;
        op[0]  = (unsigned short)cvt_pk_bf16(o[oti][0][r], o[oti][0][r]);
        op[16] = (unsigned short)cvt_pk_bf16(o[oti][1][r], o[oti][1][r]);
      }
    }
}

extern "C" void kernel_launch(void* const* d_in, const int* in_sizes, int n_in,
                              void* d_out, int out_size, void* d_ws, size_t ws_size,
                              hipStream_t stream)
{
  const float* x       = (const float*)d_in[0];   // 32*56*56*384
  const float* w_qkv   = (const float*)d_in[1];   // 1152*384
  const float* b_qkv   = (const float*)d_in[2];   // 1152
  const float* rel_pos = (const float*)d_in[3];   // 12*169
  const float* w_out   = (const float*)d_in[4];   // 384*384
  const float* b_out   = (const float*)d_in[5];   // 384
  float* out = (float*)d_out;                     // 100352*384

  char* ws = (char*)d_ws;
  unsigned short* wqb = (unsigned short*)ws;                  // 884736 B
  unsigned short* wob = (unsigned short*)(ws + 884736);       // 294912 B
  float* btab         = (float*)(ws + 884736 + 294912);       // 196608 B
  unsigned short* qws = (unsigned short*)(ws + 1376256);      // 38535168 elems
  unsigned short* kws = qws + 38535168;
  unsigned short* vws = kws + 38535168;
  unsigned short* xb  = vws + 38535168;   // x_bf during GEMM1, attn-out after
  unsigned short* ao  = xb;               // total ws ~309.7 MB

  convert_x_kernel<<<dim3(37632), dim3(256), 0, stream>>>(x, xb);
  convert_w_kernel<<<dim3(576),   dim3(256), 0, stream>>>(w_qkv, w_out, wqb, wob);
  build_btab<<<dim3(48), dim3(256), 0, stream>>>(rel_pos, btab);
  gemm128<0,9><<<dim3(7056), dim3(256), 0, stream>>>(xb, wqb, b_qkv, qws, kws, vws, nullptr);
  attn_kernel<<<dim3(6144), dim3(256), 0, stream>>>(qws, kws, vws, btab, ao);
  gemm128<1,3><<<dim3(2352), dim3(256), 0, stream>>>(ao, wob, b_out, nullptr, nullptr, nullptr, out);
}